// Round 6
// baseline (334.543 us; speedup 1.0000x reference)
//
#include <hip/hip_runtime.h>

#define DEVI static __device__ __forceinline__

using s16x8 = __attribute__((ext_vector_type(8))) short;
using f32x4 = __attribute__((ext_vector_type(4))) float;
using u32x4 = __attribute__((ext_vector_type(4))) unsigned int;

static constexpr int H  = 16;
static constexpr int S  = 1024;
static constexpr int DM = 1024;
static constexpr int NB = 2;          // batch
static constexpr int BS = NB * S;     // 2048
static constexpr long SS  = (long)S * S;
static constexpr long HSS = (long)H * SS;
static constexpr long SDM = (long)S * DM;

DEVI unsigned short f2bf(float f) {
    union { float f; unsigned u; } c; c.f = f;
    c.u += 0x7FFFu + ((c.u >> 16) & 1u);   // RNE
    return (unsigned short)(c.u >> 16);
}
DEVI float bf2f(unsigned short v) {
    union { unsigned u; float f; } c; c.u = ((unsigned)v) << 16;
    return c.f;
}

// async global->LDS, 16 bytes per lane; lds dest = wave-uniform base + lane*16
DEVI void gload16(const unsigned short* g, unsigned short* l) {
    __builtin_amdgcn_global_load_lds(
        (const __attribute__((address_space(1))) unsigned int*)g,
        (__attribute__((address_space(3))) unsigned int*)l, 16, 0, 0);
}

enum { EPI_BFB = 0, EPI_VTB, EPI_PACK, EPI_PACK2, EPI_MASK, EPI_BF, EPI_OUT };

// ---------------------------------------------------------------------------
// gemm8: 256x256-tile, BK=64, 512 thr (8 waves 2Mx4N, each 128x64 out),
// double-buffered 128KB LDS, 4 phases/K-tile:
//   p: {stage 1/4 of K-tile t+1 -> buf^1 ; 12 ds_read_b128 quad p ; setprio(1)
//       16 MFMA ; setprio(0) ; sched_barrier(0) ; s_barrier}
// Single counted wait per K-tile at p0 (vmcnt(0)+s_barrier): certifies buf b
// (loads issued 3-4 phases earlier) AND frees buf^1 (all reads done, pinned
// before barrier by data-dep lgkm waits + sched_barrier(0)).
// A,B,O: S x S per z (stride SS); B row-major [n][k]; out = epi(A.B^T).
// Grid must be (4,4,32). XCD z-group swizzle + longest-K-first built in.
// ---------------------------------------------------------------------------
template<int EPI, bool CK, bool CS>
__global__ __launch_bounds__(512)
void gemm8(const unsigned short* __restrict__ Aall,
           const unsigned short* __restrict__ Ball,
           unsigned short* __restrict__ Oall, int K)
{
    const int L   = (int)blockIdx.x + ((int)blockIdx.y << 2) + ((int)blockIdx.z << 4);
    const int xcd = L & 7, idx = L >> 3;
    const int bz  = xcd + ((idx >> 4) << 3);          // head-group -> one XCD
    const int by  = 3 - ((idx >> 2) & 3);             // longest-K first
    const int bx  = idx & 3;
    const int m0 = by * 256, n0 = bx * 256;
    if (CS && n0 > m0 + 255) return;
    const unsigned short* Ap = Aall + (long)bz * SS;
    const unsigned short* Bp = Ball + (long)bz * SS;

    __shared__ alignas(16) unsigned short lds[65536];  // [2 buf][A 16384 | B 16384]

    const int tid = threadIdx.x, w = tid >> 6, lane = tid & 63;
    const int lr = lane & 15, lg = lane >> 4;
    const int wm = w >> 2, wn = w & 3;                // wave tile: rows wm*128, cols wn*64

    // staging: 2048 16B-chunks per 256x64 operand tile, 4 insts/thread
    const unsigned short* gA[4]; const unsigned short* gB[4]; int lo[4];
#pragma unroll
    for (int i = 0; i < 4; ++i) {
        const int c = i * 512 + w * 64 + lane, row = c >> 3, slot = c & 7;
        const int gs = (slot ^ (row & 7)) * 8;        // pre-swizzled source
        gA[i] = Ap + (long)(m0 + row) * S + gs;
        gB[i] = Bp + (long)(n0 + row) * S + gs;
        lo[i] = (i * 512 + w * 64) * 8;               // wave-uniform LDS base (shorts)
    }

    f32x4 acc[8][4] = {};
    const int Keff = CK ? ((K < m0 + 256) ? K : m0 + 256) : K;
    const int nt = Keff >> 6;

#define STAGE_A(T, B) do { const long ko_ = (long)(T) << 6;                    \
    gload16(gA[0] + ko_, lds + (B) * 16384 + lo[0]);                           \
    gload16(gA[1] + ko_, lds + (B) * 16384 + lo[1]);                           \
    gload16(gA[2] + ko_, lds + (B) * 16384 + lo[2]);                           \
    gload16(gA[3] + ko_, lds + (B) * 16384 + lo[3]); } while (0)
#define STAGE_B(T, B) do { const long ko_ = (long)(T) << 6;                    \
    gload16(gB[0] + ko_, lds + 32768 + (B) * 16384 + lo[0]);                   \
    gload16(gB[1] + ko_, lds + 32768 + (B) * 16384 + lo[1]);                   \
    gload16(gB[2] + ko_, lds + 32768 + (B) * 16384 + lo[2]);                   \
    gload16(gB[3] + ko_, lds + 32768 + (B) * 16384 + lo[3]); } while (0)

    // one C-quadrant (64 rows x 32 cols per wave) x K=64: 12 ds_read + 16 MFMA
#define QUAD(R2, C2) do {                                                      \
    s16x8 qa[4][2], qb[2][2];                                                  \
    _Pragma("unroll") for (int f = 0; f < 4; ++f) {                            \
        const int ra = wm * 128 + (R2) * 64 + f * 16 + lr;                     \
        const int rx = (ra & 7) * 8;                                           \
        qa[f][0] = *reinterpret_cast<const s16x8*>(&lAb[ra * 64 + ((8 * lg) ^ rx)]);        \
        qa[f][1] = *reinterpret_cast<const s16x8*>(&lAb[ra * 64 + ((32 + 8 * lg) ^ rx)]);   \
    }                                                                          \
    _Pragma("unroll") for (int f = 0; f < 2; ++f) {                            \
        const int rb = wn * 64 + (C2) * 32 + f * 16 + lr;                      \
        const int rx = (rb & 7) * 8;                                           \
        qb[f][0] = *reinterpret_cast<const s16x8*>(&lBb[rb * 64 + ((8 * lg) ^ rx)]);        \
        qb[f][1] = *reinterpret_cast<const s16x8*>(&lBb[rb * 64 + ((32 + 8 * lg) ^ rx)]);   \
    }                                                                          \
    __builtin_amdgcn_s_setprio(1);                                             \
    _Pragma("unroll") for (int f = 0; f < 4; ++f)                              \
        _Pragma("unroll") for (int g = 0; g < 2; ++g) {                        \
            acc[(R2)*4+f][(C2)*2+g] = __builtin_amdgcn_mfma_f32_16x16x32_bf16( \
                qa[f][0], qb[g][0], acc[(R2)*4+f][(C2)*2+g], 0, 0, 0);         \
            acc[(R2)*4+f][(C2)*2+g] = __builtin_amdgcn_mfma_f32_16x16x32_bf16( \
                qa[f][1], qb[g][1], acc[(R2)*4+f][(C2)*2+g], 0, 0, 0);         \
        }                                                                      \
    __builtin_amdgcn_s_setprio(0);                                             \
} while (0)

#define PHASE_END do { __builtin_amdgcn_sched_barrier(0);                      \
    __builtin_amdgcn_s_barrier();                                              \
    __builtin_amdgcn_sched_barrier(0); } while (0)

    // prologue: stage K-tile 0 into buf 0
    STAGE_A(0, 0); STAGE_B(0, 0);

    for (int t = 0; t < nt; ++t) {
        const int b = t & 1;
        const unsigned short* lAb = lds + b * 16384;
        const unsigned short* lBb = lds + 32768 + b * 16384;
        // p0: certify buf b (its loads were issued 3-4 phases ago) and free buf b^1
        asm volatile("s_waitcnt vmcnt(0)" ::: "memory");
        __builtin_amdgcn_s_barrier();
        __builtin_amdgcn_sched_barrier(0);
        if (t + 1 < nt) STAGE_A(t + 1, b ^ 1);
        QUAD(0, 0);
        PHASE_END;
        // p1
        if (t + 1 < nt) STAGE_B(t + 1, b ^ 1);
        QUAD(0, 1);
        PHASE_END;
        // p2
        QUAD(1, 0);
        PHASE_END;
        // p3 (no trailing barrier; next iter's p0 sync covers it)
        QUAD(1, 1);
        __builtin_amdgcn_sched_barrier(0);
    }
#undef STAGE_A
#undef STAGE_B
#undef QUAD
#undef PHASE_END

    const long obase = (long)bz * SS;
#pragma unroll
    for (int fm = 0; fm < 8; ++fm)
#pragma unroll
        for (int fn = 0; fn < 4; ++fn)
#pragma unroll
            for (int r = 0; r < 4; ++r) {
                const int gm = m0 + wm * 128 + fm * 16 + lg * 4 + r;
                const int gn = n0 + wn * 64 + fn * 16 + lr;
                float vv = acc[fm][fn][r];
                const long o = obase + (long)gm * S + gn;
                if constexpr (EPI == EPI_MASK) {
                    vv = (gn <= gm) ? vv / (float)(gm + 1) : 0.f;
                    Oall[o] = f2bf(vv);
                } else {
                    Oall[o] = f2bf(vv);
                }
            }
}

// ---------------------------------------------------------------------------
// gemmS: 128x128-tile m97-structure GEMM (verified round 5) for the small ops
// ---------------------------------------------------------------------------
template<int EPI, bool CK, bool CS, bool SWZ, bool REVY>
__global__ __launch_bounds__(256)
void gemmS(const unsigned short* __restrict__ Aall, long a_sb, long a_sh, int lda,
           const unsigned short* __restrict__ Ball, long b_sb, long b_sh, int ldb,
           void* __restrict__ Oall, void* __restrict__ O2, long o_sb, long o_sh, int ldo,
           const float* __restrict__ bias, int bstride, int K, int NV)
{
    int bx, by, bz;
    if (SWZ) {   // grid must be (8,8,32)
        const int L = (int)blockIdx.x + ((int)blockIdx.y << 3) + ((int)blockIdx.z << 6);
        const int g = L & 7, r = L >> 3;
        bz = g + ((r >> 6) << 3);
        bx = r & 7;
        by = 7 - ((r >> 3) & 7);                 // longest-K first
    } else {
        bx = blockIdx.x;
        by = REVY ? (int)gridDim.y - 1 - (int)blockIdx.y : (int)blockIdx.y;
        bz = blockIdx.z;
    }
    const int m0 = by * 128, n0 = bx * 128;
    if (CS && n0 > m0 + 127) return;
    const int zb = bz >> 4, zh = bz & 15;
    const unsigned short* Ap = Aall + (long)zb * a_sb + (long)zh * a_sh;
    const unsigned short* Bp = Ball + (long)zb * b_sb + (long)zh * b_sh;
    const float* bi = bias + (long)zh * bstride;

    __shared__ alignas(16) unsigned short lA[128 * 64];
    __shared__ alignas(16) unsigned short lB[128 * 64];

    const int tid = threadIdx.x, w = tid >> 6, lane = tid & 63;
    const int lr = lane & 15, lg = lane >> 4;
    const int wm = (w >> 1) << 6, wn = (w & 1) << 6;

    const unsigned short* gA[4]; const unsigned short* gB[4]; int lo[4];
#pragma unroll
    for (int i = 0; i < 4; ++i) {
        const int q = (i * 4 + w) * 64 + lane, row = q >> 3, slot = q & 7;
        const int gs = (slot ^ (row & 7)) * 8;
        gA[i] = Ap + (long)(m0 + row) * lda + gs;
        int rb = n0 + row; if (rb >= NV) rb = NV - 1;
        gB[i] = Bp + (long)rb * ldb + gs;
        lo[i] = (i * 4 + w) * 512;
    }

    int abase[4], axor[4], bbase[4], bxor[4];
#pragma unroll
    for (int f = 0; f < 4; ++f) {
        const int ra = wm + f * 16 + lr;
        abase[f] = ra * 64; axor[f] = (ra & 7) * 8;
        const int rb = wn + f * 16 + lr;
        bbase[f] = rb * 64; bxor[f] = (rb & 7) * 8;
    }

    f32x4 acc[4][4] = {};
    const int Keff = CK ? ((K < m0 + 128) ? K : m0 + 128) : K;

    for (int k0 = 0; k0 < Keff; k0 += 64) {
#pragma unroll
        for (int i = 0; i < 4; ++i) {
            gload16(gA[i] + k0, &lA[lo[i]]);
            gload16(gB[i] + k0, &lB[lo[i]]);
        }
        __syncthreads();
#pragma unroll
        for (int kk = 0; kk < 64; kk += 32) {
            s16x8 af[4], bv[4];
#pragma unroll
            for (int f = 0; f < 4; ++f) {
                af[f] = *reinterpret_cast<const s16x8*>(&lA[abase[f] + ((kk + 8 * lg) ^ axor[f])]);
                bv[f] = *reinterpret_cast<const s16x8*>(&lB[bbase[f] + ((kk + 8 * lg) ^ bxor[f])]);
            }
#pragma unroll
            for (int fm = 0; fm < 4; ++fm)
#pragma unroll
                for (int fn = 0; fn < 4; ++fn)
                    acc[fm][fn] = __builtin_amdgcn_mfma_f32_16x16x32_bf16(af[fm], bv[fn], acc[fm][fn], 0, 0, 0);
        }
        __syncthreads();
    }

    const long obase = (long)zb * o_sb + (long)zh * o_sh;
#pragma unroll
    for (int fm = 0; fm < 4; ++fm)
#pragma unroll
        for (int fn = 0; fn < 4; ++fn) {
            const int t0 = m0 + wm + fm * 16 + lg * 4;
            const int gn = n0 + wn + fn * 16 + lr;
            if (gn >= NV) continue;
            if constexpr (EPI == EPI_PACK2) {             // dual store: P and P^T
                ushort4 pt;
                unsigned short* o1 = (unsigned short*)Oall;
                unsigned short* o2 = (unsigned short*)O2;
#pragma unroll
                for (int r = 0; r < 4; ++r) {
                    float vv = acc[fm][fn][r];
                    vv = vv > 0.f ? vv + 1.f : __expf(vv);   // elu(x)+1
                    const unsigned short b = f2bf(vv);
                    o1[obase + (long)(t0 + r) * ldo + gn] = b;
                    ((unsigned short*)&pt)[r] = b;
                }
                *reinterpret_cast<ushort4*>(&o2[obase + (long)gn * ldo + t0]) = pt;
            } else {
#pragma unroll
                for (int r = 0; r < 4; ++r) {
                    const int gm = t0 + r;
                    float vv = acc[fm][fn][r];
                    const long o = obase + (long)gm * ldo + gn;
                    if constexpr (EPI == EPI_BFB) {
                        ((unsigned short*)Oall)[o] = f2bf(vv + bi[gn]);
                    } else if constexpr (EPI == EPI_VTB) {
                        ((unsigned short*)Oall)[o] = f2bf(vv + bi[gm]);
                    } else if constexpr (EPI == EPI_PACK) {
                        vv = vv > 0.f ? vv + 1.f : __expf(vv);
                        ((unsigned short*)Oall)[o] = f2bf(vv);
                    } else if constexpr (EPI == EPI_MASK) {
                        vv = (gn <= gm) ? vv / (float)(gm + 1) : 0.f;
                        ((unsigned short*)Oall)[o] = f2bf(vv);
                    } else if constexpr (EPI == EPI_BF) {
                        ((unsigned short*)Oall)[o] = f2bf(vv);
                    } else { // EPI_OUT
                        ((float*)Oall)[o] = vv + bi[gn];
                    }
                }
            }
        }
}

// wave-per-row softmax: 4 rows/block, no cross-wave sync; 32 B/lane loads
__global__ __launch_bounds__(256)
void softmax_rows(const unsigned short* __restrict__ in, unsigned short* __restrict__ out)
{
    const int w = threadIdx.x >> 6, lane = threadIdx.x & 63;
    const long row = (long)blockIdx.x * 4 + w;
    const u32x4* r4 = reinterpret_cast<const u32x4*>(in + row * S);
    u32x4 a = r4[lane * 2], b = r4[lane * 2 + 1];
    float v[16];
#pragma unroll
    for (int i = 0; i < 4; ++i) {
        v[2*i]     = bf2f((unsigned short)(a[i] & 0xFFFF));
        v[2*i+1]   = bf2f((unsigned short)(a[i] >> 16));
        v[8+2*i]   = bf2f((unsigned short)(b[i] & 0xFFFF));
        v[8+2*i+1] = bf2f((unsigned short)(b[i] >> 16));
    }
    float mx = v[0];
#pragma unroll
    for (int i = 1; i < 16; ++i) mx = fmaxf(mx, v[i]);
#pragma unroll
    for (int off = 32; off; off >>= 1) mx = fmaxf(mx, __shfl_xor(mx, off));
    float e[16], s = 0.f;
#pragma unroll
    for (int i = 0; i < 16; ++i) { e[i] = __expf(v[i] - mx); s += e[i]; }
#pragma unroll
    for (int off = 32; off; off >>= 1) s += __shfl_xor(s, off);
    const float inv = 1.f / s;
    u32x4 oa, ob;
#pragma unroll
    for (int i = 0; i < 4; ++i) {
        oa[i] = (unsigned)f2bf(e[2*i]   * inv) | ((unsigned)f2bf(e[2*i+1]   * inv) << 16);
        ob[i] = (unsigned)f2bf(e[8+2*i] * inv) | ((unsigned)f2bf(e[8+2*i+1] * inv) << 16);
    }
    u32x4* o4 = reinterpret_cast<u32x4*>(out + row * S);
    o4[lane * 2] = oa; o4[lane * 2 + 1] = ob;
}

// z selects one of 4 sources; dst contiguous per z
__global__ __launch_bounds__(256)
void cast4(const float* __restrict__ s0, const float* __restrict__ s1,
           const float* __restrict__ s2, const float* __restrict__ s3,
           unsigned short* __restrict__ dst, int n4)
{
    const int i = blockIdx.x * 256 + threadIdx.x;
    if (i >= n4) return;
    const float* s = (blockIdx.z == 0) ? s0 : (blockIdx.z == 1) ? s1 : (blockIdx.z == 2) ? s2 : s3;
    float4 x = reinterpret_cast<const float4*>(s)[i];
    ushort4 o; o.x = f2bf(x.x); o.y = f2bf(x.y); o.z = f2bf(x.z); o.w = f2bf(x.w);
    reinterpret_cast<ushort4*>(dst + (size_t)blockIdx.z * n4 * 4)[i] = o;
}

// f32 [n][n] -> bf16 transposed [n][n], scaled; z selects src, dst contiguous
__global__ __launch_bounds__(256)
void twcast4(const float* __restrict__ s0, const float* __restrict__ s1,
             const float* __restrict__ s2, const float* __restrict__ s3,
             unsigned short* __restrict__ dstall, int n)
{
    __shared__ unsigned short t[64][72];
    const float* src = (blockIdx.z == 0) ? s0 : (blockIdx.z == 1) ? s1 : (blockIdx.z == 2) ? s2 : s3;
    const float scale = (blockIdx.z == 0) ? 0.125f : 1.0f;
    unsigned short* dst = dstall + (size_t)blockIdx.z * n * n;
    const int r0 = blockIdx.y * 64, c0 = blockIdx.x * 64;
    const int lrow = threadIdx.x >> 2, lseg = (threadIdx.x & 3) << 4;
    const float4* g4 = reinterpret_cast<const float4*>(src + (long)(r0 + lrow) * n + c0 + lseg);
    alignas(16) unsigned short tmp[16];
#pragma unroll
    for (int q = 0; q < 4; ++q) {
        float4 x = g4[q];
        tmp[4*q+0] = f2bf(x.x * scale); tmp[4*q+1] = f2bf(x.y * scale);
        tmp[4*q+2] = f2bf(x.z * scale); tmp[4*q+3] = f2bf(x.w * scale);
    }
#pragma unroll
    for (int j = 0; j < 16; ++j) t[lrow][lseg + j] = tmp[j];
    __syncthreads();
#pragma unroll
    for (int j = 0; j < 16; ++j) tmp[j] = t[lseg + j][lrow];
    unsigned short* d = dst + (long)(c0 + lrow) * n + r0 + lseg;
    *reinterpret_cast<u32x4*>(d)     = *reinterpret_cast<const u32x4*>(tmp);
    *reinterpret_cast<u32x4*>(d + 8) = *reinterpret_cast<const u32x4*>(tmp + 8);
}

// bq2[0][:] = wqb * 0.125, bq2[1][:] = wkb
__global__ __launch_bounds__(256)
void bias2(const float* __restrict__ a, const float* __restrict__ b, float* __restrict__ dst)
{
    const int i = blockIdx.x * 256 + threadIdx.x;
    if (i < DM) { dst[i] = a[i] * 0.125f; dst[DM + i] = b[i]; }
}

extern "C" void kernel_launch(void* const* d_in, const int* in_sizes, int n_in,
                              void* d_out, int out_size, void* d_ws, size_t ws_size,
                              hipStream_t stream)
{
    (void)in_sizes; (void)n_in; (void)out_size;
    const float* v_in = (const float*)d_in[0];
    const float* k_in = (const float*)d_in[1];
    const float* q_in = (const float*)d_in[2];
    const float* p_in = (const float*)d_in[3];
    const float* wq   = (const float*)d_in[4];
    const float* wqb  = (const float*)d_in[5];
    const float* wk   = (const float*)d_in[6];
    const float* wkb  = (const float*)d_in[7];
    const float* wvw  = (const float*)d_in[8];
    const float* wvb  = (const float*)d_in[9];
    const float* wc   = (const float*)d_in[10];
    const float* wcb  = (const float*)d_in[11];
    float* out = (float*)d_out;

    char* ws = (char*)d_ws;
    size_t off = 0;
    auto take = [&](size_t n) { char* p = ws + off; off += (n + 255) & ~(size_t)255; return p; };
    unsigned short* qbf = (unsigned short*)take((size_t)BS * DM * 2);  // qbf..pbf contiguous
    unsigned short* kbf = (unsigned short*)take((size_t)BS * DM * 2);
    unsigned short* vbf = (unsigned short*)take((size_t)BS * DM * 2);
    unsigned short* pbf = (unsigned short*)take((size_t)BS * DM * 2);
    unsigned short* wqT = (unsigned short*)take((size_t)DM * DM * 2);  // wqT..wcT contiguous
    unsigned short* wkT = (unsigned short*)take((size_t)DM * DM * 2);
    unsigned short* wvT = (unsigned short*)take((size_t)DM * DM * 2);
    unsigned short* wcT = (unsigned short*)take((size_t)DM * DM * 2);
    float*          bq2 = (float*)take((size_t)2 * DM * 4);
    unsigned short* qh  = (unsigned short*)take((size_t)BS * DM * 2);  // qh,kh contiguous
    unsigned short* kh  = (unsigned short*)take((size_t)BS * DM * 2);
    unsigned short* vhT = (unsigned short*)take((size_t)BS * DM * 2);
    unsigned short* ao  = (unsigned short*)take((size_t)BS * DM * 2);
    const size_t ssz = (size_t)NB * HSS * 2;
    unsigned short* B1 = (unsigned short*)take(ssz);
    unsigned short* B2 = (unsigned short*)take(ssz);
    unsigned short* B3 = (unsigned short*)take(ssz);
    const bool dual = (ws_size >= off + ssz);          // 4th S x S buffer fits?
    unsigned short* B4 = dual ? (unsigned short*)take(ssz) : nullptr;
    (void)kbf; (void)wkT;

    const int n4 = BS * DM / 4;
    const dim3 blk(256);

    cast4<<<dim3(n4 / 256, 1, 4), blk, 0, stream>>>(q_in, k_in, v_in, p_in, qbf, n4);
    twcast4<<<dim3(16, 16, 4), blk, 0, stream>>>(wq, wk, wvw, wc, wqT, DM);
    bias2<<<dim3(4), blk, 0, stream>>>(wqb, wkb, bq2);

    // q,k projections merged over z (alpha folded into wqT/bq2)
    gemmS<EPI_BFB,false,false,false,false><<<dim3(8, 16, 2), blk, 0, stream>>>(
        qbf, 0, (long)BS*DM, DM,  wqT, 0, (long)DM*DM, DM,  qh, nullptr, 0, (long)BS*DM, DM,
        bq2, DM, DM, DM);
    // vhT[b][dm][t] = (v@wv + b)^T
    gemmS<EPI_VTB,false,false,false,false><<<dim3(8, 8, 2), blk, 0, stream>>>(
        wvT, 0, 0, DM,  vbf, 0, SDM, DM,  vhT, nullptr, 0, (long)DM*S, S,
        wvb, 0, DM, S);

    unsigned short *sqkbuf, *ptbuf, *pbuf = B1, *lbuf;
    if (dual) {
        // P -> B1, P^T -> B2 in one pass
        gemmS<EPI_PACK2,false,false,true,false><<<dim3(8, 8, 32), blk, 0, stream>>>(
            qh, SDM, 64, DM,  pbf, SDM, 64, DM,  B1, B2, HSS, SS, S,  wvb, 0, 64, S);
        ptbuf = B2; sqkbuf = B3; lbuf = B4;
    } else {
        // packT[s][t] = elu(ph[s].qh[t])+1 -> B1
        gemmS<EPI_PACK,false,false,true,false><<<dim3(8, 8, 32), blk, 0, stream>>>(
            pbf, SDM, 64, DM,  qh, SDM, 64, DM,  B1, nullptr, HSS, SS, S,  wvb, 0, 64, S);
        ptbuf = B1; sqkbuf = B2; lbuf = B3;
    }
    // sQK[t][s] = (qh.kh) * tril/(t+1)
    gemmS<EPI_MASK,false,true,true,false><<<dim3(8, 8, 32), blk, 0, stream>>>(
        qh, SDM, 64, DM,  kh, SDM, 64, DM,  sqkbuf, nullptr, HSS, SS, S,  wvb, 0, 64, S);
    // unpack (logits) = sQK @ P  (B = P^T rows j), causal-K -> lbuf (bf16), 256^2 8-phase
    gemm8<EPI_BF,true,false><<<dim3(4, 4, 32), dim3(512), 0, stream>>>(
        sqkbuf, ptbuf, lbuf, S);
    // softmax: lbuf -> sqkbuf (sQK dead)
    softmax_rows<<<dim3(NB*H*S/4), blk, 0, stream>>>(lbuf, sqkbuf);
    if (!dual) {
        // pack[t][s] = elu(qh.ph)+1 -> B1 (packT dead)
        gemmS<EPI_PACK,false,false,true,false><<<dim3(8, 8, 32), blk, 0, stream>>>(
            qh, SDM, 64, DM,  pbf, SDM, 64, DM,  B1, nullptr, HSS, SS, S,  wvb, 0, 64, S);
    }
    // s2[t][s] = (sm . P[s,:]) * tril/(t+1)  (full K) -> lbuf (logits dead), 256^2 8-phase
    gemm8<EPI_MASK,false,true><<<dim3(4, 4, 32), dim3(512), 0, stream>>>(
        sqkbuf, pbuf, lbuf, S);
    // attn_out[t][d] = s2 @ vh (B = vhT head-slice [d][s], NV=64), causal-K
    gemmS<EPI_BF,true,false,false,true><<<dim3(1, 8, 32), blk, 0, stream>>>(
        lbuf, HSS, SS, S,  vhT, (long)DM*S, (long)64*S, S,  ao, nullptr, SDM, 64, DM,
        wvb, 0, S, 64);
    // out = ao @ wc + b (f32)
    gemmS<EPI_OUT,false,false,false,false><<<dim3(8, 16, 1), blk, 0, stream>>>(
        ao, 0, 0, DM,  wcT, 0, 0, DM,  out, nullptr, 0, 0, DM,  wcb, 0, DM, DM);
}

// Round 7
// 307.938 us; speedup vs baseline: 1.0864x; 1.0864x over previous
//
#include <hip/hip_runtime.h>

#define DEVI static __device__ __forceinline__

using s16x8 = __attribute__((ext_vector_type(8))) short;
using f32x4 = __attribute__((ext_vector_type(4))) float;
using u32x4 = __attribute__((ext_vector_type(4))) unsigned int;

static constexpr int H  = 16;
static constexpr int S  = 1024;
static constexpr int DM = 1024;
static constexpr int NB = 2;          // batch
static constexpr int BS = NB * S;     // 2048
static constexpr long SS  = (long)S * S;
static constexpr long HSS = (long)H * SS;
static constexpr long SDM = (long)S * DM;

DEVI unsigned short f2bf(float f) {
    union { float f; unsigned u; } c; c.f = f;
    c.u += 0x7FFFu + ((c.u >> 16) & 1u);   // RNE
    return (unsigned short)(c.u >> 16);
}
DEVI float bf2f(unsigned short v) {
    union { unsigned u; float f; } c; c.u = ((unsigned)v) << 16;
    return c.f;
}

// async global->LDS, 16 bytes per lane; lds dest = wave-uniform base + lane*16
DEVI void gload16(const unsigned short* g, unsigned short* l) {
    __builtin_amdgcn_global_load_lds(
        (const __attribute__((address_space(1))) unsigned int*)g,
        (__attribute__((address_space(3))) unsigned int*)l, 16, 0, 0);
}

enum { EPI_BFB = 0, EPI_VTB, EPI_PACK, EPI_PACK2, EPI_MASK, EPI_EXP, EPI_SMASK, EPI_BF, EPI_OUT };

// ---------------------------------------------------------------------------
// gemmT: TMxTN-tile, BK=64, single-buffer m97 loop (verified round 5), LDS
// XOR-swizzle via pre-swizzled global source + swizzled ds_read.
// (TM/64)*(TN/64) waves, each wave a 64x64 output (4x4 16x16x32 frags).
// A row-major [m][k]; B row-major [n][k]; out[m][n] = epi(A.B^T).
// z -> (zb=z>>4, zh=z&15) strides. CK: K capped at m0+TM. CS: skip n0>m0+TM-1.
// SWZ (requires grid (8,8,32)): XCD z-group remap + longest-K-first.
// ---------------------------------------------------------------------------
template<int TM, int TN, int EPI, bool CK, bool CS, bool SWZ, bool REVY>
__global__ __launch_bounds__((TM/64)*(TN/64)*64)
void gemmT(const unsigned short* __restrict__ Aall, long a_sb, long a_sh, int lda,
           const unsigned short* __restrict__ Ball, long b_sb, long b_sh, int ldb,
           void* __restrict__ Oall, void* __restrict__ O2, long o_sb, long o_sh, int ldo,
           const float* __restrict__ bias, int bstride, int K, int NV)
{
    constexpr int WN = TN / 64, WM = TM / 64, NWV = WM * WN, NTHR = NWV * 64;
    constexpr int IA = (TM * 8) / NTHR, IB = (TN * 8) / NTHR;

    int bx, by, bz;
    if (SWZ) {   // grid must be (8,8,32)
        const int L = (int)blockIdx.x + ((int)blockIdx.y << 3) + ((int)blockIdx.z << 6);
        const int g = L & 7, r = L >> 3;
        bz = g + ((r >> 6) << 3);
        bx = r & 7;
        by = 7 - ((r >> 3) & 7);                 // longest-K first
    } else {
        bx = blockIdx.x;
        by = REVY ? (int)gridDim.y - 1 - (int)blockIdx.y : (int)blockIdx.y;
        bz = blockIdx.z;
    }
    const int m0 = by * TM, n0 = bx * TN;
    if (CS && n0 > m0 + TM - 1) return;
    const int zb = bz >> 4, zh = bz & 15;
    const unsigned short* Ap = Aall + (long)zb * a_sb + (long)zh * a_sh;
    const unsigned short* Bp = Ball + (long)zb * b_sb + (long)zh * b_sh;
    const float* bi = bias + (long)zh * bstride;

    __shared__ alignas(16) unsigned short lA[TM * 64];
    __shared__ alignas(16) unsigned short lB[TN * 64];

    const int tid = threadIdx.x, w = tid >> 6, lane = tid & 63;
    const int lr = lane & 15, lg = lane >> 4;
    const int wm = (w / WN) * 64, wn = (w % WN) * 64;

    const unsigned short* gA[IA]; int loA[IA];
    const unsigned short* gB[IB]; int loB[IB];
#pragma unroll
    for (int i = 0; i < IA; ++i) {
        const int q = i * NTHR + tid, row = q >> 3, slot = q & 7;
        gA[i]  = Ap + (long)(m0 + row) * lda + ((slot ^ (row & 7)) * 8);
        loA[i] = (i * NWV + w) * 512;
    }
#pragma unroll
    for (int i = 0; i < IB; ++i) {
        const int q = i * NTHR + tid, row = q >> 3, slot = q & 7;
        int rb = n0 + row; if (rb >= NV) rb = NV - 1;
        gB[i]  = Bp + (long)rb * ldb + ((slot ^ (row & 7)) * 8);
        loB[i] = (i * NWV + w) * 512;
    }

    int abase[4], axor[4], bbase[4], bxor[4];
#pragma unroll
    for (int f = 0; f < 4; ++f) {
        const int ra = wm + f * 16 + lr;
        abase[f] = ra * 64; axor[f] = (ra & 7) * 8;
        const int rb = wn + f * 16 + lr;
        bbase[f] = rb * 64; bxor[f] = (rb & 7) * 8;
    }

    f32x4 acc[4][4] = {};
    const int Keff = CK ? ((K < m0 + TM) ? K : m0 + TM) : K;

    for (int k0 = 0; k0 < Keff; k0 += 64) {
#pragma unroll
        for (int i = 0; i < IA; ++i) gload16(gA[i] + k0, &lA[loA[i]]);
#pragma unroll
        for (int i = 0; i < IB; ++i) gload16(gB[i] + k0, &lB[loB[i]]);
        __syncthreads();
#pragma unroll
        for (int kk = 0; kk < 64; kk += 32) {
            s16x8 af[4], bv[4];
#pragma unroll
            for (int f = 0; f < 4; ++f) {
                af[f] = *reinterpret_cast<const s16x8*>(&lA[abase[f] + ((kk + 8 * lg) ^ axor[f])]);
                bv[f] = *reinterpret_cast<const s16x8*>(&lB[bbase[f] + ((kk + 8 * lg) ^ bxor[f])]);
            }
#pragma unroll
            for (int fm = 0; fm < 4; ++fm)
#pragma unroll
                for (int fn = 0; fn < 4; ++fn)
                    acc[fm][fn] = __builtin_amdgcn_mfma_f32_16x16x32_bf16(af[fm], bv[fn], acc[fm][fn], 0, 0, 0);
        }
        __syncthreads();
    }

    const long obase = (long)zb * o_sb + (long)zh * o_sh;
#pragma unroll
    for (int fm = 0; fm < 4; ++fm)
#pragma unroll
        for (int fn = 0; fn < 4; ++fn) {
            const int t0 = m0 + wm + fm * 16 + lg * 4;
            const int gn = n0 + wn + fn * 16 + lr;
            if (gn >= NV) continue;
            if constexpr (EPI == EPI_PACK2) {             // dual store: P and P^T
                ushort4 pt;
                unsigned short* o1 = (unsigned short*)Oall;
                unsigned short* o2 = (unsigned short*)O2;
#pragma unroll
                for (int r = 0; r < 4; ++r) {
                    float vv = acc[fm][fn][r];
                    vv = vv > 0.f ? vv + 1.f : __expf(vv);   // elu(x)+1
                    const unsigned short b = f2bf(vv);
                    o1[obase + (long)(t0 + r) * ldo + gn] = b;
                    ((unsigned short*)&pt)[r] = b;
                }
                *reinterpret_cast<ushort4*>(&o2[obase + (long)gn * ldo + t0]) = pt;
            } else {
#pragma unroll
                for (int r = 0; r < 4; ++r) {
                    const int gm = t0 + r;
                    float vv = acc[fm][fn][r];
                    const long o = obase + (long)gm * ldo + gn;
                    if constexpr (EPI == EPI_BFB) {
                        ((unsigned short*)Oall)[o] = f2bf(vv + bi[gn]);
                    } else if constexpr (EPI == EPI_VTB) {
                        ((unsigned short*)Oall)[o] = f2bf(vv + bi[gm]);
                    } else if constexpr (EPI == EPI_PACK) {
                        vv = vv > 0.f ? vv + 1.f : __expf(vv);
                        ((unsigned short*)Oall)[o] = f2bf(vv);
                    } else if constexpr (EPI == EPI_MASK) {
                        vv = (gn <= gm) ? vv / (float)(gm + 1) : 0.f;
                        ((unsigned short*)Oall)[o] = f2bf(vv);
                    } else if constexpr (EPI == EPI_EXP) {
                        ((unsigned short*)Oall)[o] = f2bf(__expf(vv));   // unnormalized exp
                    } else if constexpr (EPI == EPI_SMASK) {
                        // bias = inv row-sums laid out [32 z][S]
                        vv = (gn <= gm) ? vv * bias[(long)bz * S + gm] / (float)(gm + 1) : 0.f;
                        ((unsigned short*)Oall)[o] = f2bf(vv);
                    } else if constexpr (EPI == EPI_BF) {
                        ((unsigned short*)Oall)[o] = f2bf(vv);
                    } else { // EPI_OUT
                        ((float*)Oall)[o] = vv + bi[gn];
                    }
                }
            }
        }
}

// wave-per-row reciprocal row-sum: inv[row] = 1 / sum_j E[row][j]
__global__ __launch_bounds__(256)
void rowsum_inv(const unsigned short* __restrict__ E, float* __restrict__ inv)
{
    const int w = threadIdx.x >> 6, lane = threadIdx.x & 63;
    const long row = (long)blockIdx.x * 4 + w;
    const u32x4* r4 = reinterpret_cast<const u32x4*>(E + row * S);
    u32x4 a = r4[lane * 2], b = r4[lane * 2 + 1];
    float s = 0.f;
#pragma unroll
    for (int i = 0; i < 4; ++i) {
        s += bf2f((unsigned short)(a[i] & 0xFFFF)) + bf2f((unsigned short)(a[i] >> 16));
        s += bf2f((unsigned short)(b[i] & 0xFFFF)) + bf2f((unsigned short)(b[i] >> 16));
    }
#pragma unroll
    for (int off = 32; off; off >>= 1) s += __shfl_xor(s, off);
    if (lane == 0) inv[row] = 1.f / s;
}

// z selects one of 4 sources; dst contiguous per z
__global__ __launch_bounds__(256)
void cast4(const float* __restrict__ s0, const float* __restrict__ s1,
           const float* __restrict__ s2, const float* __restrict__ s3,
           unsigned short* __restrict__ dst, int n4)
{
    const int i = blockIdx.x * 256 + threadIdx.x;
    if (i >= n4) return;
    const float* s = (blockIdx.z == 0) ? s0 : (blockIdx.z == 1) ? s1 : (blockIdx.z == 2) ? s2 : s3;
    float4 x = reinterpret_cast<const float4*>(s)[i];
    ushort4 o; o.x = f2bf(x.x); o.y = f2bf(x.y); o.z = f2bf(x.z); o.w = f2bf(x.w);
    reinterpret_cast<ushort4*>(dst + (size_t)blockIdx.z * n4 * 4)[i] = o;
}

// f32 [n][n] -> bf16 transposed [n][n], scaled; z selects src, dst contiguous
__global__ __launch_bounds__(256)
void twcast4(const float* __restrict__ s0, const float* __restrict__ s1,
             const float* __restrict__ s2, const float* __restrict__ s3,
             unsigned short* __restrict__ dstall, int n)
{
    __shared__ unsigned short t[64][72];
    const float* src = (blockIdx.z == 0) ? s0 : (blockIdx.z == 1) ? s1 : (blockIdx.z == 2) ? s2 : s3;
    const float scale = (blockIdx.z == 0) ? 0.125f : 1.0f;
    unsigned short* dst = dstall + (size_t)blockIdx.z * n * n;
    const int r0 = blockIdx.y * 64, c0 = blockIdx.x * 64;
    const int lrow = threadIdx.x >> 2, lseg = (threadIdx.x & 3) << 4;
    const float4* g4 = reinterpret_cast<const float4*>(src + (long)(r0 + lrow) * n + c0 + lseg);
    alignas(16) unsigned short tmp[16];
#pragma unroll
    for (int q = 0; q < 4; ++q) {
        float4 x = g4[q];
        tmp[4*q+0] = f2bf(x.x * scale); tmp[4*q+1] = f2bf(x.y * scale);
        tmp[4*q+2] = f2bf(x.z * scale); tmp[4*q+3] = f2bf(x.w * scale);
    }
#pragma unroll
    for (int j = 0; j < 16; ++j) t[lrow][lseg + j] = tmp[j];
    __syncthreads();
#pragma unroll
    for (int j = 0; j < 16; ++j) tmp[j] = t[lseg + j][lrow];
    unsigned short* d = dst + (long)(c0 + lrow) * n + r0 + lseg;
    *reinterpret_cast<u32x4*>(d)     = *reinterpret_cast<const u32x4*>(tmp);
    *reinterpret_cast<u32x4*>(d + 8) = *reinterpret_cast<const u32x4*>(tmp + 8);
}

// bq2[0][:] = wqb * 0.125, bq2[1][:] = wkb
__global__ __launch_bounds__(256)
void bias2(const float* __restrict__ a, const float* __restrict__ b, float* __restrict__ dst)
{
    const int i = blockIdx.x * 256 + threadIdx.x;
    if (i < DM) { dst[i] = a[i] * 0.125f; dst[DM + i] = b[i]; }
}

extern "C" void kernel_launch(void* const* d_in, const int* in_sizes, int n_in,
                              void* d_out, int out_size, void* d_ws, size_t ws_size,
                              hipStream_t stream)
{
    (void)in_sizes; (void)n_in; (void)out_size;
    const float* v_in = (const float*)d_in[0];
    const float* k_in = (const float*)d_in[1];
    const float* q_in = (const float*)d_in[2];
    const float* p_in = (const float*)d_in[3];
    const float* wq   = (const float*)d_in[4];
    const float* wqb  = (const float*)d_in[5];
    const float* wk   = (const float*)d_in[6];
    const float* wkb  = (const float*)d_in[7];
    const float* wvw  = (const float*)d_in[8];
    const float* wvb  = (const float*)d_in[9];
    const float* wc   = (const float*)d_in[10];
    const float* wcb  = (const float*)d_in[11];
    float* out = (float*)d_out;

    char* ws = (char*)d_ws;
    size_t off = 0;
    auto take = [&](size_t n) { char* p = ws + off; off += (n + 255) & ~(size_t)255; return p; };
    unsigned short* qbf = (unsigned short*)take((size_t)BS * DM * 2);  // qbf..pbf contiguous
    unsigned short* kbf = (unsigned short*)take((size_t)BS * DM * 2);
    unsigned short* vbf = (unsigned short*)take((size_t)BS * DM * 2);
    unsigned short* pbf = (unsigned short*)take((size_t)BS * DM * 2);
    unsigned short* wqT = (unsigned short*)take((size_t)DM * DM * 2);  // wqT..wcT contiguous
    unsigned short* wkT = (unsigned short*)take((size_t)DM * DM * 2);
    unsigned short* wvT = (unsigned short*)take((size_t)DM * DM * 2);
    unsigned short* wcT = (unsigned short*)take((size_t)DM * DM * 2);
    float*          bq2 = (float*)take((size_t)2 * DM * 4);
    float*          inv = (float*)take((size_t)NB * H * S * 4);
    unsigned short* qh  = (unsigned short*)take((size_t)BS * DM * 2);  // qh,kh contiguous
    unsigned short* kh  = (unsigned short*)take((size_t)BS * DM * 2);
    unsigned short* vhT = (unsigned short*)take((size_t)BS * DM * 2);
    unsigned short* ao  = (unsigned short*)take((size_t)BS * DM * 2);
    const size_t ssz = (size_t)NB * HSS * 2;
    unsigned short* B1 = (unsigned short*)take(ssz);
    unsigned short* B2 = (unsigned short*)take(ssz);
    unsigned short* B3 = (unsigned short*)take(ssz);
    const bool dual = (ws_size >= off + ssz);          // 4th S x S buffer fits?
    unsigned short* B4 = dual ? (unsigned short*)take(ssz) : nullptr;
    (void)kbf; (void)wkT;

    const int n4 = BS * DM / 4;
    const dim3 b256(256), b128(128);

    cast4<<<dim3(n4 / 256, 1, 4), b256, 0, stream>>>(q_in, k_in, v_in, p_in, qbf, n4);
    twcast4<<<dim3(16, 16, 4), b256, 0, stream>>>(wq, wk, wvw, wc, wqT, DM);
    bias2<<<dim3(4), b256, 0, stream>>>(wqb, wkb, bq2);

    // q,k projections merged over z (alpha folded into wqT/bq2), 64x128 tiles
    gemmT<64,128,EPI_BFB,false,false,false,false><<<dim3(8, 32, 2), b128, 0, stream>>>(
        qbf, 0, (long)BS*DM, DM,  wqT, 0, (long)DM*DM, DM,  qh, nullptr, 0, (long)BS*DM, DM,
        bq2, DM, DM, DM);
    // vhT[b][dm][t] = (v@wv + b)^T, 64x128 tiles
    gemmT<64,128,EPI_VTB,false,false,false,false><<<dim3(8, 16, 2), b128, 0, stream>>>(
        wvT, 0, 0, DM,  vbf, 0, SDM, DM,  vhT, nullptr, 0, (long)DM*S, S,
        wvb, 0, DM, S);

    unsigned short *sqkbuf, *ptbuf, *pbuf, *ebuf, *s2buf;
    if (dual) {
        // P -> B1, P^T -> B2 in one pass
        gemmT<128,128,EPI_PACK2,false,false,true,false><<<dim3(8, 8, 32), b256, 0, stream>>>(
            qh, SDM, 64, DM,  pbf, SDM, 64, DM,  B1, B2, HSS, SS, S,  wvb, 0, 64, S);
        pbuf = B1; ptbuf = B2; sqkbuf = B3; ebuf = B4; s2buf = B3;
    } else {
        // packT[s][t] = elu(ph[s].qh[t])+1 -> B1
        gemmT<128,128,EPI_PACK,false,false,true,false><<<dim3(8, 8, 32), b256, 0, stream>>>(
            pbf, SDM, 64, DM,  qh, SDM, 64, DM,  B1, nullptr, HSS, SS, S,  wvb, 0, 64, S);
        ptbuf = B1; sqkbuf = B2; ebuf = B3; pbuf = B1; s2buf = B2;
    }
    // sQK[t][s] = (qh.kh) * tril/(t+1)
    gemmT<128,128,EPI_MASK,false,true,true,false><<<dim3(8, 8, 32), b256, 0, stream>>>(
        qh, SDM, 64, DM,  kh, SDM, 64, DM,  sqkbuf, nullptr, HSS, SS, S,  wvb, 0, 64, S);
    // E = exp(sQK @ P) (B = P^T rows j), causal-K -> ebuf (bf16, unnormalized)
    gemmT<128,128,EPI_EXP,true,false,true,false><<<dim3(8, 8, 32), b256, 0, stream>>>(
        sqkbuf, HSS, SS, S,  ptbuf, HSS, SS, S,  ebuf, nullptr, HSS, SS, S,  wvb, 0, S, S);
    // inv[row] = 1 / rowsum(E)
    rowsum_inv<<<dim3(NB*H*S/4), b256, 0, stream>>>(ebuf, inv);
    if (!dual) {
        // pack[t][s] = elu(qh.ph)+1 -> B1 (packT dead)
        gemmT<128,128,EPI_PACK,false,false,true,false><<<dim3(8, 8, 32), b256, 0, stream>>>(
            qh, SDM, 64, DM,  pbf, SDM, 64, DM,  B1, nullptr, HSS, SS, S,  wvb, 0, 64, S);
    }
    // s2[t][s] = (E[t,:].P[s,:]) * inv[t] * tril/(t+1)  (full K) -> s2buf (sQK dead)
    gemmT<128,128,EPI_SMASK,false,true,true,false><<<dim3(8, 8, 32), b256, 0, stream>>>(
        ebuf, HSS, SS, S,  pbuf, HSS, SS, S,  s2buf, nullptr, HSS, SS, S,  inv, 0, S, S);
    // attn_out[t][d] = s2 @ vh (B = vhT head-slice [d][s]), 128x64 tiles, causal-K
    gemmT<128,64,EPI_BF,true,false,false,true><<<dim3(1, 8, 32), b128, 0, stream>>>(
        s2buf, HSS, SS, S,  vhT, (long)DM*S, (long)64*S, S,  ao, nullptr, SDM, 64, DM,
        wvb, 0, S, 64);
    // out = ao @ wc + b (f32), 64x128 tiles
    gemmT<64,128,EPI_OUT,false,false,false,false><<<dim3(8, 32, 1), b128, 0, stream>>>(
        ao, 0, 0, DM,  wcT, 0, 0, DM,  out, nullptr, 0, 0, DM,  wcb, 0, DM, DM);
}